// Round 3
// baseline (51.288 us; speedup 1.0000x reference)
//
#include <hip/hip_runtime.h>

#define N_STATES 12
#define MAX_OBS 50
#define TABLE_SIZE (N_STATES * MAX_OBS)  // 600 entries

// Kernel 1: build the 600-entry log-prob table in double precision.
// lp(s, o) = m*log(phi/(m+phi)) + o*log(m/(m+phi)) + lgamma(o+m) - lgamma(o+1) - lgamma(m)
__global__ void build_table_kernel(const float* __restrict__ state_means,
                                   const float* __restrict__ state_phis,
                                   float* __restrict__ table) {
    int t = blockIdx.x * blockDim.x + threadIdx.x;
    if (t >= TABLE_SIZE) return;
    int s = t / MAX_OBS;
    int o = t % MAX_OBS;
    double m  = (double)state_means[s];
    double ph = (double)state_phis[s];
    double ob = (double)o;
    double log_denom = log(m + ph);
    double log_p   = log(m)  - log_denom;
    double log_1mp = log(ph) - log_denom;
    double lp = m * log_1mp + ob * log_p
              + lgamma(ob + m) - lgamma(ob + 1.0) - lgamma(m);
    table[t] = (float)lp;
}

// Consume one float4/int4 pair via the LDS table.
#define CONS(o, s) (lut[(s).x * MAX_OBS + (int)(o).x] + \
                    lut[(s).y * MAX_OBS + (int)(o).y] + \
                    lut[(s).z * MAX_OBS + (int)(o).z] + \
                    lut[(s).w * MAX_OBS + (int)(o).w])

// Kernel 2: stream obs+states fully software-pipelined (named-scalar stages so
// regalloc keeps loads in flight), LDS table lookup, hierarchical sum.
// __launch_bounds__(256, 6): 6 blocks/CU (75% occupancy) -> ~84 VGPR budget,
// enough to keep 5-7 dwordx4 load-pairs live per thread.
__global__ void __launch_bounds__(256, 6) nb_sum_kernel(const float* __restrict__ obs,
                                                        const int* __restrict__ states,
                                                        const float* __restrict__ table,
                                                        float* __restrict__ out,
                                                        int n) {
    __shared__ float lut[TABLE_SIZE];
    for (int i = threadIdx.x; i < TABLE_SIZE; i += blockDim.x)
        lut[i] = table[i];
    __syncthreads();

    float acc = 0.0f;
    const int tid = blockIdx.x * blockDim.x + threadIdx.x;
    const int nthreads = gridDim.x * blockDim.x;
    const int n4 = n >> 2;
    const float4* __restrict__ obs4 = (const float4*)obs;
    const int4*  __restrict__ st4  = (const int4*)states;

    if (n4 == (nthreads << 3)) {
        // Fast path: exactly 8 vec4 granules per thread, fully unrolled
        // software pipeline. Issue 5 load-pairs, then alternate
        // {issue next pair, consume oldest} so >=4 pairs stay in flight.
        const int i0 = tid;
        float4 o0 = obs4[i0];                int4 s0 = st4[i0];
        float4 o1 = obs4[i0 + 1 * nthreads]; int4 s1 = st4[i0 + 1 * nthreads];
        float4 o2 = obs4[i0 + 2 * nthreads]; int4 s2 = st4[i0 + 2 * nthreads];
        float4 o3 = obs4[i0 + 3 * nthreads]; int4 s3 = st4[i0 + 3 * nthreads];
        float4 o4 = obs4[i0 + 4 * nthreads]; int4 s4 = st4[i0 + 4 * nthreads];
        float a0 = CONS(o0, s0);
        float4 o5 = obs4[i0 + 5 * nthreads]; int4 s5 = st4[i0 + 5 * nthreads];
        float a1 = CONS(o1, s1);
        float4 o6 = obs4[i0 + 6 * nthreads]; int4 s6 = st4[i0 + 6 * nthreads];
        float a2 = CONS(o2, s2);
        float4 o7 = obs4[i0 + 7 * nthreads]; int4 s7 = st4[i0 + 7 * nthreads];
        float a3 = CONS(o3, s3);
        a0 += CONS(o4, s4);
        a1 += CONS(o5, s5);
        a2 += CONS(o6, s6);
        a3 += CONS(o7, s7);
        acc = (a0 + a1) + (a2 + a3);
    } else {
        // Generic path (not hit at N=16777216 with 2048x256).
        for (int i = tid; i < n4; i += nthreads) {
            float4 o = obs4[i];
            int4   s = st4[i];
            acc += CONS(o, s);
        }
        for (int i = (n4 << 2) + tid; i < n; i += nthreads)
            acc += lut[states[i] * MAX_OBS + (int)obs[i]];
    }

    // wave64 butterfly reduce
    #pragma unroll
    for (int off = 32; off > 0; off >>= 1)
        acc += __shfl_down(acc, off, 64);

    __shared__ float wsum[4];  // 256 threads / 64 lanes
    const int lane = threadIdx.x & 63;
    const int wid  = threadIdx.x >> 6;
    if (lane == 0) wsum[wid] = acc;
    __syncthreads();
    if (threadIdx.x == 0) {
        float s = wsum[0] + wsum[1] + wsum[2] + wsum[3];
        atomicAdd(out, s);
    }
}

extern "C" void kernel_launch(void* const* d_in, const int* in_sizes, int n_in,
                              void* d_out, int out_size, void* d_ws, size_t ws_size,
                              hipStream_t stream) {
    const float* obs         = (const float*)d_in[0];
    const int*   states      = (const int*)d_in[1];
    const float* state_means = (const float*)d_in[2];
    const float* state_phis  = (const float*)d_in[3];
    float* out   = (float*)d_out;
    float* table = (float*)d_ws;
    const int n = in_sizes[0];

    // d_out is poisoned (0xAA) before timing and never re-poisoned between
    // replays -> zero it every call, on-stream (graph-capture safe).
    hipMemsetAsync(out, 0, sizeof(float), stream);

    build_table_kernel<<<dim3((TABLE_SIZE + 255) / 256), dim3(256), 0, stream>>>(
        state_means, state_phis, table);

    nb_sum_kernel<<<dim3(2048), dim3(256), 0, stream>>>(obs, states, table, out, n);
}

// Round 4
// 46.527 us; speedup vs baseline: 1.1023x; 1.1023x over previous
//
#include <hip/hip_runtime.h>

#define N_STATES 12
#define MAX_OBS 50
#define TABLE_SIZE (N_STATES * MAX_OBS)  // 600 entries

// Kernel 1: build the 600-entry log-prob table in double precision,
// and zero the output accumulator (replaces a separate memset dispatch).
// lp(s, o) = m*log(phi/(m+phi)) + o*log(m/(m+phi)) + lgamma(o+m) - lgamma(o+1) - lgamma(m)
__global__ void build_table_kernel(const float* __restrict__ state_means,
                                   const float* __restrict__ state_phis,
                                   float* __restrict__ table,
                                   float* __restrict__ out) {
    if (blockIdx.x == 0 && threadIdx.x == 0) *out = 0.0f;  // stream-ordered before sum kernel
    int t = blockIdx.x * blockDim.x + threadIdx.x;
    if (t >= TABLE_SIZE) return;
    int s = t / MAX_OBS;
    int o = t % MAX_OBS;
    double m  = (double)state_means[s];
    double ph = (double)state_phis[s];
    double ob = (double)o;
    double log_denom = log(m + ph);
    double log_p   = log(m)  - log_denom;
    double log_1mp = log(ph) - log_denom;
    double lp = m * log_1mp + ob * log_p
              + lgamma(ob + m) - lgamma(ob + 1.0) - lgamma(m);
    table[t] = (float)lp;
}

// Kernel 2: stream obs+states. Fast path issues ALL 16 dwordx4 loads
// (8 obs4/st4 pairs, 16 KB/wave in flight) before a sched_barrier(0) fence,
// then consumes via the LDS table. launch_bounds(256,4) grants a 128-VGPR
// budget so the 64 data VGPRs stay live instead of being re-sunk by the
// machine scheduler (which is what silently happened in R2/R3 at VGPR=36).
__global__ void __launch_bounds__(256, 4) nb_sum_kernel(const float* __restrict__ obs,
                                                        const int* __restrict__ states,
                                                        const float* __restrict__ table,
                                                        float* __restrict__ out,
                                                        int n) {
    __shared__ float lut[TABLE_SIZE];
    for (int i = threadIdx.x; i < TABLE_SIZE; i += blockDim.x)
        lut[i] = table[i];
    __syncthreads();

    float acc = 0.0f;
    const int tid = blockIdx.x * blockDim.x + threadIdx.x;
    const int nthreads = gridDim.x * blockDim.x;
    const int n4 = n >> 2;
    const float4* __restrict__ obs4 = (const float4*)obs;
    const int4*  __restrict__ st4  = (const int4*)states;

    if (n4 == (nthreads << 3)) {
        // Fast path: exactly 8 vec4 granules per thread.
        float4 o[8];
        int4   s[8];
        int idx = tid;
        #pragma unroll
        for (int k = 0; k < 8; ++k) {
            o[k] = obs4[idx];
            s[k] = st4[idx];
            idx += nthreads;
        }
        // Hard scheduling fence: no instruction may cross. All 16 loads are
        // issued above; consumes stay below. One memory round-trip per wave.
        __builtin_amdgcn_sched_barrier(0);
        float a0 = 0.0f, a1 = 0.0f, a2 = 0.0f, a3 = 0.0f;
        #pragma unroll
        for (int k = 0; k < 8; ++k) {
            a0 += lut[s[k].x * MAX_OBS + (int)o[k].x];
            a1 += lut[s[k].y * MAX_OBS + (int)o[k].y];
            a2 += lut[s[k].z * MAX_OBS + (int)o[k].z];
            a3 += lut[s[k].w * MAX_OBS + (int)o[k].w];
        }
        acc = (a0 + a1) + (a2 + a3);
    } else {
        // Generic path (not hit at N=16777216 with 2048x256).
        for (int i = tid; i < n4; i += nthreads) {
            float4 o = obs4[i];
            int4   s = st4[i];
            acc += lut[s.x * MAX_OBS + (int)o.x];
            acc += lut[s.y * MAX_OBS + (int)o.y];
            acc += lut[s.z * MAX_OBS + (int)o.z];
            acc += lut[s.w * MAX_OBS + (int)o.w];
        }
        for (int i = (n4 << 2) + tid; i < n; i += nthreads)
            acc += lut[states[i] * MAX_OBS + (int)obs[i]];
    }

    // wave64 butterfly reduce
    #pragma unroll
    for (int off = 32; off > 0; off >>= 1)
        acc += __shfl_down(acc, off, 64);

    __shared__ float wsum[4];  // 256 threads / 64 lanes
    const int lane = threadIdx.x & 63;
    const int wid  = threadIdx.x >> 6;
    if (lane == 0) wsum[wid] = acc;
    __syncthreads();
    if (threadIdx.x == 0) {
        float s = wsum[0] + wsum[1] + wsum[2] + wsum[3];
        atomicAdd(out, s);
    }
}

extern "C" void kernel_launch(void* const* d_in, const int* in_sizes, int n_in,
                              void* d_out, int out_size, void* d_ws, size_t ws_size,
                              hipStream_t stream) {
    const float* obs         = (const float*)d_in[0];
    const int*   states      = (const int*)d_in[1];
    const float* state_means = (const float*)d_in[2];
    const float* state_phis  = (const float*)d_in[3];
    float* out   = (float*)d_out;
    float* table = (float*)d_ws;
    const int n = in_sizes[0];

    // build_table_kernel also zeroes *out (d_out is poisoned before timing
    // and never re-poisoned between replays).
    build_table_kernel<<<dim3((TABLE_SIZE + 255) / 256), dim3(256), 0, stream>>>(
        state_means, state_phis, table, out);

    nb_sum_kernel<<<dim3(2048), dim3(256), 0, stream>>>(obs, states, table, out, n);
}

// Round 5
// 45.510 us; speedup vs baseline: 1.1270x; 1.0223x over previous
//
#include <hip/hip_runtime.h>

#define N_STATES 12
#define MAX_OBS 50
#define TABLE_SIZE (N_STATES * MAX_OBS)  // 600 entries

// Kernel 1: build the 600-entry log-prob table in double precision,
// and zero the output accumulator (replaces a separate memset dispatch).
// lp(s, o) = m*log(phi/(m+phi)) + o*log(m/(m+phi)) + lgamma(o+m) - lgamma(o+1) - lgamma(m)
__global__ void build_table_kernel(const float* __restrict__ state_means,
                                   const float* __restrict__ state_phis,
                                   float* __restrict__ table,
                                   float* __restrict__ out) {
    if (blockIdx.x == 0 && threadIdx.x == 0) *out = 0.0f;  // stream-ordered before sum kernel
    int t = blockIdx.x * blockDim.x + threadIdx.x;
    if (t >= TABLE_SIZE) return;
    int s = t / MAX_OBS;
    int o = t % MAX_OBS;
    double m  = (double)state_means[s];
    double ph = (double)state_phis[s];
    double ob = (double)o;
    double log_denom = log(m + ph);
    double log_p   = log(m)  - log_denom;
    double log_1mp = log(ph) - log_denom;
    double lp = m * log_1mp + ob * log_p
              + lgamma(ob + m) - lgamma(ob + 1.0) - lgamma(m);
    table[t] = (float)lp;
}

// Inline-asm volatile loads: cannot be reordered against each other, and the
// "=v" outputs force regalloc to keep all destinations live -> a REAL
// 16-deep load pipeline (8 KB/wave in flight), which the compiler refused to
// build from C++ (R2-R4 all collapsed to depth-2, VGPR=36).
#define GLOADF4(dst, ptr) \
    asm volatile("global_load_dwordx4 %0, %1, off" : "=v"(dst) : "v"(ptr))
#define GLOADI4(dst, ptr) \
    asm volatile("global_load_dwordx4 %0, %1, off" : "=v"(dst) : "v"(ptr))
// Counted wait + scheduling fence (guide rule #18: VALU can hoist past an
// inline-asm waitcnt unless a sched_barrier(0) immediately follows).
#define VMWAIT(n) do { \
    asm volatile("s_waitcnt vmcnt(" #n ")" ::: "memory"); \
    __builtin_amdgcn_sched_barrier(0); \
} while (0)

#define CONS(o, s) (lut[(s).x * MAX_OBS + (int)(o).x] + \
                    lut[(s).y * MAX_OBS + (int)(o).y] + \
                    lut[(s).z * MAX_OBS + (int)(o).z] + \
                    lut[(s).w * MAX_OBS + (int)(o).w])

__global__ void __launch_bounds__(256, 4) nb_sum_kernel(const float* __restrict__ obs,
                                                        const int* __restrict__ states,
                                                        const float* __restrict__ table,
                                                        float* __restrict__ out,
                                                        int n) {
    __shared__ float lut[TABLE_SIZE];
    for (int i = threadIdx.x; i < TABLE_SIZE; i += blockDim.x)
        lut[i] = table[i];
    __syncthreads();

    float acc = 0.0f;
    const int tid = blockIdx.x * blockDim.x + threadIdx.x;
    const int nthreads = gridDim.x * blockDim.x;
    const int n4 = n >> 2;
    const float4* __restrict__ obs4 = (const float4*)obs;
    const int4*  __restrict__ st4  = (const int4*)states;

    if (n4 == (nthreads << 3)) {
        // Fast path: exactly 8 vec4 granules per thread.
        // Issue all 16 dwordx4 loads (in-order, volatile), then consume each
        // pair behind a counted vmcnt so early consumes overlap late arrivals.
        float4 o0, o1, o2, o3, o4, o5, o6, o7;
        int4   s0, s1, s2, s3, s4, s5, s6, s7;
        GLOADF4(o0, obs4 + tid + 0 * nthreads);  GLOADI4(s0, st4 + tid + 0 * nthreads);
        GLOADF4(o1, obs4 + tid + 1 * nthreads);  GLOADI4(s1, st4 + tid + 1 * nthreads);
        GLOADF4(o2, obs4 + tid + 2 * nthreads);  GLOADI4(s2, st4 + tid + 2 * nthreads);
        GLOADF4(o3, obs4 + tid + 3 * nthreads);  GLOADI4(s3, st4 + tid + 3 * nthreads);
        GLOADF4(o4, obs4 + tid + 4 * nthreads);  GLOADI4(s4, st4 + tid + 4 * nthreads);
        GLOADF4(o5, obs4 + tid + 5 * nthreads);  GLOADI4(s5, st4 + tid + 5 * nthreads);
        GLOADF4(o6, obs4 + tid + 6 * nthreads);  GLOADI4(s6, st4 + tid + 6 * nthreads);
        GLOADF4(o7, obs4 + tid + 7 * nthreads);  GLOADI4(s7, st4 + tid + 7 * nthreads);

        float a0 = 0.0f, a1 = 0.0f, a2 = 0.0f, a3 = 0.0f;
        VMWAIT(14); a0 += CONS(o0, s0);
        VMWAIT(12); a1 += CONS(o1, s1);
        VMWAIT(10); a2 += CONS(o2, s2);
        VMWAIT(8);  a3 += CONS(o3, s3);
        VMWAIT(6);  a0 += CONS(o4, s4);
        VMWAIT(4);  a1 += CONS(o5, s5);
        VMWAIT(2);  a2 += CONS(o6, s6);
        VMWAIT(0);  a3 += CONS(o7, s7);
        acc = (a0 + a1) + (a2 + a3);
    } else {
        // Generic path (not hit at N=16777216 with 2048x256).
        for (int i = tid; i < n4; i += nthreads) {
            float4 o = obs4[i];
            int4   s = st4[i];
            acc += CONS(o, s);
        }
        for (int i = (n4 << 2) + tid; i < n; i += nthreads)
            acc += lut[states[i] * MAX_OBS + (int)obs[i]];
    }

    // wave64 butterfly reduce
    #pragma unroll
    for (int off = 32; off > 0; off >>= 1)
        acc += __shfl_down(acc, off, 64);

    __shared__ float wsum[4];  // 256 threads / 64 lanes
    const int lane = threadIdx.x & 63;
    const int wid  = threadIdx.x >> 6;
    if (lane == 0) wsum[wid] = acc;
    __syncthreads();
    if (threadIdx.x == 0) {
        float s = wsum[0] + wsum[1] + wsum[2] + wsum[3];
        atomicAdd(out, s);
    }
}

extern "C" void kernel_launch(void* const* d_in, const int* in_sizes, int n_in,
                              void* d_out, int out_size, void* d_ws, size_t ws_size,
                              hipStream_t stream) {
    const float* obs         = (const float*)d_in[0];
    const int*   states      = (const int*)d_in[1];
    const float* state_means = (const float*)d_in[2];
    const float* state_phis  = (const float*)d_in[3];
    float* out   = (float*)d_out;
    float* table = (float*)d_ws;
    const int n = in_sizes[0];

    // build_table_kernel also zeroes *out (d_out is poisoned before timing
    // and never re-poisoned between replays).
    build_table_kernel<<<dim3((TABLE_SIZE + 255) / 256), dim3(256), 0, stream>>>(
        state_means, state_phis, table, out);

    nb_sum_kernel<<<dim3(2048), dim3(256), 0, stream>>>(obs, states, table, out, n);
}

// Round 6
// 42.546 us; speedup vs baseline: 1.2055x; 1.0697x over previous
//
#include <hip/hip_runtime.h>

#define N_STATES 12
#define MAX_OBS 50
#define TABLE_SIZE (N_STATES * MAX_OBS)  // 600 entries
#define NBLOCKS 2048

// d_ws layout: [0 .. TABLE_SIZE) table | [TABLE_SIZE .. TABLE_SIZE+NBLOCKS) block partials

// Kernel 1: build the 600-entry log-prob table in double precision.
// lp(s, o) = m*log(phi/(m+phi)) + o*log(m/(m+phi)) + lgamma(o+m) - lgamma(o+1) - lgamma(m)
__global__ void build_table_kernel(const float* __restrict__ state_means,
                                   const float* __restrict__ state_phis,
                                   float* __restrict__ table) {
    int t = blockIdx.x * blockDim.x + threadIdx.x;
    if (t >= TABLE_SIZE) return;
    int s = t / MAX_OBS;
    int o = t % MAX_OBS;
    double m  = (double)state_means[s];
    double ph = (double)state_phis[s];
    double ob = (double)o;
    double log_denom = log(m + ph);
    double log_p   = log(m)  - log_denom;
    double log_1mp = log(ph) - log_denom;
    double lp = m * log_1mp + ob * log_p
              + lgamma(ob + m) - lgamma(ob + 1.0) - lgamma(m);
    table[t] = (float)lp;
}

// Inline-asm volatile loads: in-order issue, outputs pinned live -> deep MLP.
#define GLOADF4(dst, ptr) \
    asm volatile("global_load_dwordx4 %0, %1, off" : "=v"(dst) : "v"(ptr))
#define GLOADI4(dst, ptr) \
    asm volatile("global_load_dwordx4 %0, %1, off" : "=v"(dst) : "v"(ptr))
#define VMWAIT(n) do { \
    asm volatile("s_waitcnt vmcnt(" #n ")" ::: "memory"); \
    __builtin_amdgcn_sched_barrier(0); \
} while (0)

#define CONS(o, s) (lut[(s).x * MAX_OBS + (int)(o).x] + \
                    lut[(s).y * MAX_OBS + (int)(o).y] + \
                    lut[(s).z * MAX_OBS + (int)(o).z] + \
                    lut[(s).w * MAX_OBS + (int)(o).w])

// Kernel 2: stream obs+states -> per-block partial sums in d_ws.
// NO atomics: R1-R5 were floored at ~47us by 2048 serialized same-address
// device-scope atomicAdds (evidence: L3-resident replays with FETCH=65KB ran
// at the same duration -> not memory-bound; all pipes <5% busy).
__global__ void __launch_bounds__(256, 4) nb_sum_kernel(const float* __restrict__ obs,
                                                        const int* __restrict__ states,
                                                        const float* __restrict__ table,
                                                        float* __restrict__ partials,
                                                        int n) {
    __shared__ float lut[TABLE_SIZE];
    for (int i = threadIdx.x; i < TABLE_SIZE; i += blockDim.x)
        lut[i] = table[i];
    __syncthreads();

    float acc = 0.0f;
    const int tid = blockIdx.x * blockDim.x + threadIdx.x;
    const int nthreads = gridDim.x * blockDim.x;
    const int n4 = n >> 2;
    const float4* __restrict__ obs4 = (const float4*)obs;
    const int4*  __restrict__ st4  = (const int4*)states;

    if (n4 == (nthreads << 3)) {
        // Fast path: exactly 8 vec4 granules per thread; 16 dwordx4 loads in
        // flight, consumed behind counted vmcnt.
        float4 o0, o1, o2, o3, o4, o5, o6, o7;
        int4   s0, s1, s2, s3, s4, s5, s6, s7;
        GLOADF4(o0, obs4 + tid + 0 * nthreads);  GLOADI4(s0, st4 + tid + 0 * nthreads);
        GLOADF4(o1, obs4 + tid + 1 * nthreads);  GLOADI4(s1, st4 + tid + 1 * nthreads);
        GLOADF4(o2, obs4 + tid + 2 * nthreads);  GLOADI4(s2, st4 + tid + 2 * nthreads);
        GLOADF4(o3, obs4 + tid + 3 * nthreads);  GLOADI4(s3, st4 + tid + 3 * nthreads);
        GLOADF4(o4, obs4 + tid + 4 * nthreads);  GLOADI4(s4, st4 + tid + 4 * nthreads);
        GLOADF4(o5, obs4 + tid + 5 * nthreads);  GLOADI4(s5, st4 + tid + 5 * nthreads);
        GLOADF4(o6, obs4 + tid + 6 * nthreads);  GLOADI4(s6, st4 + tid + 6 * nthreads);
        GLOADF4(o7, obs4 + tid + 7 * nthreads);  GLOADI4(s7, st4 + tid + 7 * nthreads);

        float a0 = 0.0f, a1 = 0.0f, a2 = 0.0f, a3 = 0.0f;
        VMWAIT(14); a0 += CONS(o0, s0);
        VMWAIT(12); a1 += CONS(o1, s1);
        VMWAIT(10); a2 += CONS(o2, s2);
        VMWAIT(8);  a3 += CONS(o3, s3);
        VMWAIT(6);  a0 += CONS(o4, s4);
        VMWAIT(4);  a1 += CONS(o5, s5);
        VMWAIT(2);  a2 += CONS(o6, s6);
        VMWAIT(0);  a3 += CONS(o7, s7);
        acc = (a0 + a1) + (a2 + a3);
    } else {
        // Generic path (not hit at N=16777216 with 2048x256).
        for (int i = tid; i < n4; i += nthreads) {
            float4 o = obs4[i];
            int4   s = st4[i];
            acc += CONS(o, s);
        }
        for (int i = (n4 << 2) + tid; i < n; i += nthreads)
            acc += lut[states[i] * MAX_OBS + (int)obs[i]];
    }

    // wave64 butterfly reduce
    #pragma unroll
    for (int off = 32; off > 0; off >>= 1)
        acc += __shfl_down(acc, off, 64);

    __shared__ float wsum[4];  // 256 threads / 64 lanes
    const int lane = threadIdx.x & 63;
    const int wid  = threadIdx.x >> 6;
    if (lane == 0) wsum[wid] = acc;
    __syncthreads();
    if (threadIdx.x == 0)
        partials[blockIdx.x] = wsum[0] + wsum[1] + wsum[2] + wsum[3];
}

// Kernel 3: reduce NBLOCKS partials -> *out. Single block, no atomics.
__global__ void __launch_bounds__(256) final_reduce_kernel(const float* __restrict__ partials,
                                                           float* __restrict__ out) {
    float acc = 0.0f;
    for (int i = threadIdx.x; i < NBLOCKS; i += 256)
        acc += partials[i];
    #pragma unroll
    for (int off = 32; off > 0; off >>= 1)
        acc += __shfl_down(acc, off, 64);
    __shared__ float wsum[4];
    const int lane = threadIdx.x & 63;
    const int wid  = threadIdx.x >> 6;
    if (lane == 0) wsum[wid] = acc;
    __syncthreads();
    if (threadIdx.x == 0)
        *out = wsum[0] + wsum[1] + wsum[2] + wsum[3];
}

extern "C" void kernel_launch(void* const* d_in, const int* in_sizes, int n_in,
                              void* d_out, int out_size, void* d_ws, size_t ws_size,
                              hipStream_t stream) {
    const float* obs         = (const float*)d_in[0];
    const int*   states      = (const int*)d_in[1];
    const float* state_means = (const float*)d_in[2];
    const float* state_phis  = (const float*)d_in[3];
    float* out      = (float*)d_out;
    float* table    = (float*)d_ws;
    float* partials = table + TABLE_SIZE;
    const int n = in_sizes[0];

    build_table_kernel<<<dim3((TABLE_SIZE + 255) / 256), dim3(256), 0, stream>>>(
        state_means, state_phis, table);

    nb_sum_kernel<<<dim3(NBLOCKS), dim3(256), 0, stream>>>(obs, states, table, partials, n);

    // Single writer of *out -> no pre-zeroing needed (harness poison is
    // overwritten every call).
    final_reduce_kernel<<<dim3(1), dim3(256), 0, stream>>>(partials, out);
}

// Round 7
// 31.734 us; speedup vs baseline: 1.6162x; 1.3407x over previous
//
#include <hip/hip_runtime.h>

#define N_STATES 12
#define MAX_OBS 50
#define TABLE_SIZE (N_STATES * MAX_OBS)  // 600 bins
#define SUM_BLOCKS 512
#define SUM_THREADS 512

// d_ws layout: [0..600) table | [600..600+SUM_BLOCKS) block partials

// Kernel 1: 600-entry log-prob table in double precision.
// lp(s,o) = m*log(phi/(m+phi)) + o*log(m/(m+phi)) + lgamma(o+m) - lgamma(o+1) - lgamma(m)
__global__ void build_table_kernel(const float* __restrict__ state_means,
                                   const float* __restrict__ state_phis,
                                   float* __restrict__ table) {
    int t = blockIdx.x * blockDim.x + threadIdx.x;
    if (t >= TABLE_SIZE) return;
    int s = t / MAX_OBS;
    int o = t % MAX_OBS;
    double m  = (double)state_means[s];
    double ph = (double)state_phis[s];
    double ob = (double)o;
    double log_denom = log(m + ph);
    double log_p   = log(m)  - log_denom;
    double log_1mp = log(ph) - log_denom;
    double lp = m * log_1mp + ob * log_p
              + lgamma(ob + m) - lgamma(ob + 1.0) - lgamma(m);
    table[t] = (float)lp;
}

// Kernel 2: per-block 600-bin LDS histogram of (state,obs), then one dot
// product with the table. The hot loop has NO LDS-read dependency: ds_add_u32
// is fire-and-forget (result unused -> no lgkmcnt wait), so the only chain is
// load -> addr-calc -> atomic-issue. This ablates the per-element
// load->ds_read->wait->fadd serialization that survived R1-R6.
__global__ void __launch_bounds__(SUM_THREADS, 4) nb_hist_kernel(const float* __restrict__ obs,
                                                                 const int* __restrict__ states,
                                                                 const float* __restrict__ table,
                                                                 float* __restrict__ partials,
                                                                 int n) {
    __shared__ unsigned int hist[TABLE_SIZE];
    for (int i = threadIdx.x; i < TABLE_SIZE; i += blockDim.x)
        hist[i] = 0u;
    __syncthreads();

    const int tid = blockIdx.x * blockDim.x + threadIdx.x;
    const int nthreads = gridDim.x * blockDim.x;
    const int n4 = n >> 2;
    const float4* __restrict__ obs4 = (const float4*)obs;
    const int4*  __restrict__ st4  = (const int4*)states;

    #pragma unroll 4
    for (int i = tid; i < n4; i += nthreads) {
        float4 o = obs4[i];
        int4   s = st4[i];
        atomicAdd(&hist[s.x * MAX_OBS + (int)o.x], 1u);
        atomicAdd(&hist[s.y * MAX_OBS + (int)o.y], 1u);
        atomicAdd(&hist[s.z * MAX_OBS + (int)o.z], 1u);
        atomicAdd(&hist[s.w * MAX_OBS + (int)o.w], 1u);
    }
    for (int i = (n4 << 2) + tid; i < n; i += nthreads)
        atomicAdd(&hist[states[i] * MAX_OBS + (int)obs[i]], 1u);
    __syncthreads();

    // Per-block dot: counts are exact integers (<2^24, exact in float).
    float acc = 0.0f;
    for (int i = threadIdx.x; i < TABLE_SIZE; i += blockDim.x)
        acc += (float)hist[i] * table[i];

    // wave64 butterfly reduce
    #pragma unroll
    for (int off = 32; off > 0; off >>= 1)
        acc += __shfl_down(acc, off, 64);

    __shared__ float wsum[SUM_THREADS / 64];
    const int lane = threadIdx.x & 63;
    const int wid  = threadIdx.x >> 6;
    if (lane == 0) wsum[wid] = acc;
    __syncthreads();
    if (threadIdx.x == 0) {
        float s = 0.0f;
        #pragma unroll
        for (int w = 0; w < SUM_THREADS / 64; ++w) s += wsum[w];
        partials[blockIdx.x] = s;
    }
}

// Kernel 3: reduce SUM_BLOCKS partials -> *out. Single block, single writer.
__global__ void __launch_bounds__(SUM_BLOCKS) final_reduce_kernel(const float* __restrict__ partials,
                                                                  float* __restrict__ out) {
    float acc = partials[threadIdx.x];  // SUM_BLOCKS == blockDim.x
    #pragma unroll
    for (int off = 32; off > 0; off >>= 1)
        acc += __shfl_down(acc, off, 64);
    __shared__ float wsum[SUM_BLOCKS / 64];
    const int lane = threadIdx.x & 63;
    const int wid  = threadIdx.x >> 6;
    if (lane == 0) wsum[wid] = acc;
    __syncthreads();
    if (threadIdx.x == 0) {
        float s = 0.0f;
        #pragma unroll
        for (int w = 0; w < SUM_BLOCKS / 64; ++w) s += wsum[w];
        *out = s;
    }
}

extern "C" void kernel_launch(void* const* d_in, const int* in_sizes, int n_in,
                              void* d_out, int out_size, void* d_ws, size_t ws_size,
                              hipStream_t stream) {
    const float* obs         = (const float*)d_in[0];
    const int*   states      = (const int*)d_in[1];
    const float* state_means = (const float*)d_in[2];
    const float* state_phis  = (const float*)d_in[3];
    float* out      = (float*)d_out;
    float* table    = (float*)d_ws;
    float* partials = table + TABLE_SIZE;
    const int n = in_sizes[0];

    build_table_kernel<<<dim3((TABLE_SIZE + 255) / 256), dim3(256), 0, stream>>>(
        state_means, state_phis, table);

    nb_hist_kernel<<<dim3(SUM_BLOCKS), dim3(SUM_THREADS), 0, stream>>>(
        obs, states, table, partials, n);

    final_reduce_kernel<<<dim3(1), dim3(SUM_BLOCKS), 0, stream>>>(partials, out);
}